// Round 1
// baseline (2501.852 us; speedup 1.0000x reference)
//
#include <hip/hip_runtime.h>

#define BB 4
#define LL 1024
#define HH 16
#define DD 64
#define BLHD (BB*LL*HH*DD)   // 4194304
#define BLH  (BB*LL*HH)      // 65536

// XOR swizzle keyed on (row & 15); shifts are multiples of 4 floats so float4
// contiguity/alignment is preserved. Spreads a 64-lane wave's b128 reads
// evenly over all 32 LDS banks.
__device__ __forceinline__ int swz(int row) {
    return (((row & 7) << 3) ^ (((row >> 3) & 1) << 2));
}

// ---------------------------------------------------------------------------
// K1: C[4096,1024] = A[4096,1024] @ W[1024,1024]^T + bias   (f32, 64x64 tile)
// ---------------------------------------------------------------------------
__global__ __launch_bounds__(256) void gemm_qkv(
    const float* __restrict__ A, const float* __restrict__ W,
    const float* __restrict__ bias, float* __restrict__ C) {
    __shared__ float As[16][64];
    __shared__ float Ws[16][64];
    const int tid = threadIdx.x;
    const int bm = blockIdx.y << 6, bn = blockIdx.x << 6;
    const int tr = (tid >> 4) << 2, tc = (tid & 15) << 2;
    const int lr = tid >> 2, lk = (tid & 3) << 2;
    float acc[4][4] = {};
    const float* Aptr = A + (size_t)(bm + lr) * 1024 + lk;
    const float* Wptr = W + (size_t)(bn + lr) * 1024 + lk;
    for (int k0 = 0; k0 < 1024; k0 += 16) {
        const float4 av = *(const float4*)(Aptr + k0);
        const float4 wv = *(const float4*)(Wptr + k0);
        __syncthreads();
        As[lk + 0][lr] = av.x; As[lk + 1][lr] = av.y;
        As[lk + 2][lr] = av.z; As[lk + 3][lr] = av.w;
        Ws[lk + 0][lr] = wv.x; Ws[lk + 1][lr] = wv.y;
        Ws[lk + 2][lr] = wv.z; Ws[lk + 3][lr] = wv.w;
        __syncthreads();
#pragma unroll
        for (int kk = 0; kk < 16; ++kk) {
            const float4 a = *(const float4*)&As[kk][tr];
            const float4 b = *(const float4*)&Ws[kk][tc];
            acc[0][0] += a.x*b.x; acc[0][1] += a.x*b.y; acc[0][2] += a.x*b.z; acc[0][3] += a.x*b.w;
            acc[1][0] += a.y*b.x; acc[1][1] += a.y*b.y; acc[1][2] += a.y*b.z; acc[1][3] += a.y*b.w;
            acc[2][0] += a.z*b.x; acc[2][1] += a.z*b.y; acc[2][2] += a.z*b.z; acc[2][3] += a.z*b.w;
            acc[3][0] += a.w*b.x; acc[3][1] += a.w*b.y; acc[3][2] += a.w*b.z; acc[3][3] += a.w*b.w;
        }
    }
    const float4 bv = *(const float4*)&bias[bn + tc];
#pragma unroll
    for (int i = 0; i < 4; ++i) {
        float4 o;
        o.x = acc[i][0] + bv.x; o.y = acc[i][1] + bv.y;
        o.z = acc[i][2] + bv.z; o.w = acc[i][3] + bv.w;
        *(float4*)&C[(size_t)(bm + tr + i) * 1024 + bn + tc] = o;
    }
}

// ---------------------------------------------------------------------------
// K2: per-head transform  q2 = q @ Wsq,  k2 = k @ Wsk,  qb = q.bsq, kb = k.bsk
//     q viewed as [65536 rows, 64]; Wsq indexed [d][e] (row-major [D,D])
// ---------------------------------------------------------------------------
__global__ __launch_bounds__(256) void headproj(
    const float* __restrict__ q, const float* __restrict__ k,
    const float* __restrict__ Wsq, const float* __restrict__ bsq,
    const float* __restrict__ Wsk, const float* __restrict__ bsk,
    float* __restrict__ q2, float* __restrict__ k2,
    float* __restrict__ qb, float* __restrict__ kb) {
    __shared__ float WqS[64 * 64], WkS[64 * 64];
    __shared__ float Qs[16 * 64], Ks[16 * 64];
    __shared__ float bqS[64], bkS[64];
    const int tid = threadIdx.x;
    const int row0 = blockIdx.x << 4;
#pragma unroll
    for (int i = 0; i < 4; ++i) {
        const int f = (tid + i * 256) << 2;
        *(float4*)&WqS[f] = *(const float4*)&Wsq[f];
        *(float4*)&WkS[f] = *(const float4*)&Wsk[f];
    }
    {
        const int rw = tid >> 4, d0 = (tid & 15) << 2;
        *(float4*)&Qs[(rw << 6) + d0] = *(const float4*)&q[((size_t)(row0 + rw) << 6) + d0];
        *(float4*)&Ks[(rw << 6) + d0] = *(const float4*)&k[((size_t)(row0 + rw) << 6) + d0];
    }
    if (tid < 64) { bqS[tid] = bsq[tid]; bkS[tid] = bsk[tid]; }
    __syncthreads();
    const int row = tid >> 4, e0 = (tid & 15) << 2;
    float aq[4] = {}, ak[4] = {};
    for (int dd = 0; dd < 64; ++dd) {
        const float qd = Qs[(row << 6) + dd];
        const float kd = Ks[(row << 6) + dd];
        const float4 wq = *(const float4*)&WqS[(dd << 6) + e0];
        const float4 wk = *(const float4*)&WkS[(dd << 6) + e0];
        aq[0] += qd * wq.x; aq[1] += qd * wq.y; aq[2] += qd * wq.z; aq[3] += qd * wq.w;
        ak[0] += kd * wk.x; ak[1] += kd * wk.y; ak[2] += kd * wk.z; ak[3] += kd * wk.w;
    }
    {
        float4 o; o.x = aq[0]; o.y = aq[1]; o.z = aq[2]; o.w = aq[3];
        *(float4*)&q2[((size_t)(row0 + row) << 6) + e0] = o;
        float4 p; p.x = ak[0]; p.y = ak[1]; p.z = ak[2]; p.w = ak[3];
        *(float4*)&k2[((size_t)(row0 + row) << 6) + e0] = p;
    }
    if ((tid & 15) == 0) {
        float a = 0.f, c = 0.f;
        for (int dd = 0; dd < 64; ++dd) {
            a += Qs[(row << 6) + dd] * bqS[dd];
            c += Ks[(row << 6) + dd] * bkS[dd];
        }
        qb[row0 + row] = a; kb[row0 + row] = c;
    }
}

// ---------------------------------------------------------------------------
// K3: scores[b,h,l,r] = (q.k + S[l,r,:].(q2_l + k2_r) + qb + kb)/8 + mask
//     Block = one 16x16 (l,r) tile; S tile staged ONCE (64KB LDS, swizzled);
//     loop over all 64 (b,h) inside the block so HBM reads S exactly once.
// ---------------------------------------------------------------------------
__global__ __launch_bounds__(256) void scores_kernel(
    const float* __restrict__ q, const float* __restrict__ k,
    const float* __restrict__ q2, const float* __restrict__ k2,
    const float* __restrict__ qb, const float* __restrict__ kb,
    const float* __restrict__ S, const float* __restrict__ mask,
    float* __restrict__ out) {
    __shared__ float Ss[256 * 64];               // 64 KB
    __shared__ float Qs[16 * 64], Q2s[16 * 64];  // 4 KB each
    __shared__ float Ks[16 * 64], K2s[16 * 64];
    const int tid = threadIdx.x;
    const int bl = blockIdx.y << 4, br = blockIdx.x << 4;
    const int l = tid >> 4, r = tid & 15;

    // stage S tile: thread t owns global row (l,r) = (t>>4, t&15)
    {
        const size_t sbase = ((size_t)(bl + l) * 1024 + (br + r)) * 64;
        const int sw = swz(tid);
#pragma unroll
        for (int i = 0; i < 16; ++i) {
            const int d0 = i << 2;
            *(float4*)&Ss[(tid << 6) + (d0 ^ sw)] = *(const float4*)&S[sbase + d0];
        }
    }

    const int swl = swz(l), swr = swz(r), swt = swz(tid);
    for (int bh = 0; bh < 64; ++bh) {
        const int b = bh >> 4, h = bh & 15;
        __syncthreads();   // previous iter's compute done (also covers S stage)
        {
            const int rw = tid >> 4;
            const int d0 = (tid & 15) << 2;
            const int sww = swz(rw);
            const size_t qidx = (((size_t)b * 1024 + bl + rw) * 16 + h) * 64 + d0;
            const size_t kidx = (((size_t)b * 1024 + br + rw) * 16 + h) * 64 + d0;
            *(float4*)&Qs [(rw << 6) + (d0 ^ sww)] = *(const float4*)&q [qidx];
            *(float4*)&Q2s[(rw << 6) + (d0 ^ sww)] = *(const float4*)&q2[qidx];
            *(float4*)&Ks [(rw << 6) + (d0 ^ sww)] = *(const float4*)&k [kidx];
            *(float4*)&K2s[(rw << 6) + (d0 ^ sww)] = *(const float4*)&k2[kidx];
        }
        __syncthreads();
        const float base = qb[((size_t)b * 1024 + bl + l) * 16 + h]
                         + kb[((size_t)b * 1024 + br + r) * 16 + h];
        float ax = 0.f, ay = 0.f, az = 0.f, aw = 0.f;
#pragma unroll
        for (int d0 = 0; d0 < 64; d0 += 4) {
            const float4 qv  = *(const float4*)&Qs [(l << 6) + (d0 ^ swl)];
            const float4 q2v = *(const float4*)&Q2s[(l << 6) + (d0 ^ swl)];
            const float4 kv  = *(const float4*)&Ks [(r << 6) + (d0 ^ swr)];
            const float4 k2v = *(const float4*)&K2s[(r << 6) + (d0 ^ swr)];
            const float4 sv  = *(const float4*)&Ss [(tid << 6) + (d0 ^ swt)];
            ax += qv.x * kv.x + sv.x * (q2v.x + k2v.x);
            ay += qv.y * kv.y + sv.y * (q2v.y + k2v.y);
            az += qv.z * kv.z + sv.z * (q2v.z + k2v.z);
            aw += qv.w * kv.w + sv.w * (q2v.w + k2v.w);
        }
        const float res = (base + ((ax + ay) + (az + aw))) * 0.125f
                        + mask[(size_t)b * 1024 + br + r];
        out[(((size_t)b * 16 + h) * 1024 + (bl + l)) * 1024 + (br + r)] = res;
    }
}

// ---------------------------------------------------------------------------
// K4: row softmax over stored scores + PV.  Block = (bh, 16 l-rows).
// ---------------------------------------------------------------------------
__global__ __launch_bounds__(256) void softmax_pv(
    const float* __restrict__ scores, const float* __restrict__ v,
    float* __restrict__ ctx) {
    __shared__ float P[16 * 1024];   // 64 KB
    __shared__ float red[256];
    __shared__ float mrow[16], srow[16];
    const int tid = threadIdx.x;
    const int lt = blockIdx.x, bh = blockIdx.y;
    const int b = bh >> 4, h = bh & 15;
    const int row = tid >> 4, tx = tid & 15;
    const size_t sbase = ((size_t)bh * 1024 + (lt << 4)) * 1024;
#pragma unroll
    for (int j = 0; j < 16; ++j) {
        const int c = (tx + (j << 4)) << 2;
        *(float4*)&P[(row << 10) + c] = *(const float4*)&scores[sbase + ((size_t)row << 10) + c];
    }
    __syncthreads();
    float pm = -1e30f;
#pragma unroll
    for (int j = 0; j < 16; ++j) {
        const int c = (tx + (j << 4)) << 2;
        const float4 x = *(const float4*)&P[(row << 10) + c];
        pm = fmaxf(pm, fmaxf(fmaxf(x.x, x.y), fmaxf(x.z, x.w)));
    }
    red[tid] = pm;
    __syncthreads();
    if (tx == 0) {
        float m = red[tid];
        for (int j = 1; j < 16; ++j) m = fmaxf(m, red[tid + j]);
        mrow[row] = m;
    }
    __syncthreads();
    const float m = mrow[row];
    float ps = 0.f;
#pragma unroll
    for (int j = 0; j < 16; ++j) {
        const int c = (tx + (j << 4)) << 2;
        float4 x = *(const float4*)&P[(row << 10) + c];
        x.x = __expf(x.x - m); x.y = __expf(x.y - m);
        x.z = __expf(x.z - m); x.w = __expf(x.w - m);
        *(float4*)&P[(row << 10) + c] = x;
        ps += (x.x + x.y) + (x.z + x.w);
    }
    red[tid] = ps;
    __syncthreads();
    if (tx == 0) {
        float s = 0.f;
        for (int j = 0; j < 16; ++j) s += red[tid + j];
        srow[row] = s;
    }
    __syncthreads();
    const float inv = 1.0f / srow[row];
    const float* vp = v + ((size_t)b << 20) + (h << 6) + (tx << 2);
    float ax0 = 0, ay0 = 0, az0 = 0, aw0 = 0;
    float ax1 = 0, ay1 = 0, az1 = 0, aw1 = 0;
    for (int rr = 0; rr < 1024; rr += 2) {
        const float p0 = P[(row << 10) + rr];
        const float p1 = P[(row << 10) + rr + 1];
        const float4 v0 = *(const float4*)(vp + ((size_t)rr << 10));
        const float4 v1 = *(const float4*)(vp + ((size_t)(rr + 1) << 10));
        ax0 += p0 * v0.x; ay0 += p0 * v0.y; az0 += p0 * v0.z; aw0 += p0 * v0.w;
        ax1 += p1 * v1.x; ay1 += p1 * v1.y; az1 += p1 * v1.z; aw1 += p1 * v1.w;
    }
    float4 o;
    o.x = (ax0 + ax1) * inv; o.y = (ay0 + ay1) * inv;
    o.z = (az0 + az1) * inv; o.w = (aw0 + aw1) * inv;
    *(float4*)&ctx[(((size_t)b * 1024 + (lt << 4) + row) << 10) + (h << 6) + (tx << 2)] = o;
}

// ---------------------------------------------------------------------------
extern "C" void kernel_launch(void* const* d_in, const int* in_sizes, int n_in,
                              void* d_out, int out_size, void* d_ws, size_t ws_size,
                              hipStream_t stream) {
    (void)in_sizes; (void)n_in; (void)out_size; (void)ws_size;
    const float* hidden = (const float*)d_in[0];
    const float* mask   = (const float*)d_in[1];
    const float* S      = (const float*)d_in[2];
    const float* Wq  = (const float*)d_in[3];  const float* bq  = (const float*)d_in[4];
    const float* Wk  = (const float*)d_in[5];  const float* bk  = (const float*)d_in[6];
    const float* Wv  = (const float*)d_in[7];  const float* bv  = (const float*)d_in[8];
    const float* Wsq = (const float*)d_in[9];  const float* bsq = (const float*)d_in[10];
    const float* Wsk = (const float*)d_in[11]; const float* bsk = (const float*)d_in[12];

    float* ctx    = (float*)d_out;
    float* scores = ctx + (size_t)BLHD;

    float* ws = (float*)d_ws;
    float* q  = ws;
    float* k  = ws + (size_t)BLHD;
    float* v  = ws + (size_t)2 * BLHD;
    float* q2 = ws + (size_t)3 * BLHD;
    float* k2 = ws + (size_t)4 * BLHD;
    float* qb = ws + (size_t)5 * BLHD;
    float* kb = qb + BLH;

    dim3 g1(16, 64);
    gemm_qkv<<<g1, 256, 0, stream>>>(hidden, Wq, bq, q);
    gemm_qkv<<<g1, 256, 0, stream>>>(hidden, Wk, bk, k);
    gemm_qkv<<<g1, 256, 0, stream>>>(hidden, Wv, bv, v);
    headproj<<<4096, 256, 0, stream>>>(q, k, Wsq, bsq, Wsk, bsk, q2, k2, qb, kb);
    scores_kernel<<<dim3(64, 64), 256, 0, stream>>>(q, k, q2, k2, qb, kb, S, mask, scores);
    softmax_pv<<<dim3(64, 64), 256, 0, stream>>>(scores, v, ctx);
}

// Round 2
// 1718.988 us; speedup vs baseline: 1.4554x; 1.4554x over previous
//
#include <hip/hip_runtime.h>

typedef __attribute__((ext_vector_type(8))) short short8v;
typedef __attribute__((ext_vector_type(4))) short short4v;
typedef __attribute__((ext_vector_type(4))) float float4v;

#define MFMA16(a,b,c) __builtin_amdgcn_mfma_f32_16x16x32_bf16(a,b,c,0,0,0)

__device__ __forceinline__ unsigned short f2b(float f) {
    union { float f; unsigned u; } v; v.f = f;
    unsigned r = v.u + 0x7FFFu + ((v.u >> 16) & 1u);
    return (unsigned short)(r >> 16);
}
__device__ __forceinline__ float b2f(unsigned short s) {
    union { unsigned u; float f; } v; v.u = ((unsigned)s) << 16;
    return v.f;
}
__device__ __forceinline__ short8v pack8(float4v a, float4v b) {
    short8v o;
    o[0]=(short)f2b(a[0]); o[1]=(short)f2b(a[1]); o[2]=(short)f2b(a[2]); o[3]=(short)f2b(a[3]);
    o[4]=(short)f2b(b[0]); o[5]=(short)f2b(b[1]); o[6]=(short)f2b(b[2]); o[7]=(short)f2b(b[3]);
    return o;
}

// ---------------------------------------------------------------------------
// P1: f32 -> bf16 pack (8 elems/thread)
// ---------------------------------------------------------------------------
__global__ __launch_bounds__(256) void pack_bf16(
    const float* __restrict__ in, unsigned short* __restrict__ out, int n8) {
    int i = blockIdx.x * 256 + threadIdx.x;
    if (i < n8) {
        float4v a = *(const float4v*)&in[(size_t)i * 8];
        float4v b = *(const float4v*)&in[(size_t)i * 8 + 4];
        *(short8v*)&out[(size_t)i * 8] = pack8(a, b);
    }
}

// ---------------------------------------------------------------------------
// P2: C = hb @ W^T + bias  (MFMA bf16, operands direct from global)
//     vmode 0: out[bh][l][d] bf16      (qh / kh)
//     vmode 1: out[bh][d][r] bf16      (vT)
// grid (16, 32), 256 thr = 4 waves; wave covers M32 x N64; K=1024
// ---------------------------------------------------------------------------
__global__ __launch_bounds__(256) void qkv_gemm(
    const unsigned short* __restrict__ A,   // [4096][1024] bf16
    const unsigned short* __restrict__ W,   // [1024][1024] bf16 [n][k]
    const float* __restrict__ bias,         // [1024]
    unsigned short* __restrict__ out, int vmode) {
    const int wave = threadIdx.x >> 6, lane = threadIdx.x & 63;
    const int m0 = blockIdx.y * 128 + wave * 32;
    const int n0 = blockIdx.x * 64;
    const int lrow = lane & 15, g8 = (lane >> 4) << 3, row4 = (lane >> 4) << 2;
    float4v acc[2][4] = {};
    const unsigned short* Ap = A + (size_t)(m0 + lrow) * 1024 + g8;
    const unsigned short* Wp = W + (size_t)(n0 + lrow) * 1024 + g8;
#pragma unroll 2
    for (int k0 = 0; k0 < 1024; k0 += 32) {
        short8v a0 = *(const short8v*)(Ap + k0);
        short8v a1 = *(const short8v*)(Ap + 16 * 1024 + k0);
        short8v b0 = *(const short8v*)(Wp + k0);
        short8v b1 = *(const short8v*)(Wp + 16 * 1024 + k0);
        short8v b2 = *(const short8v*)(Wp + 32 * 1024 + k0);
        short8v b3 = *(const short8v*)(Wp + 48 * 1024 + k0);
        acc[0][0] = MFMA16(a0, b0, acc[0][0]); acc[0][1] = MFMA16(a0, b1, acc[0][1]);
        acc[0][2] = MFMA16(a0, b2, acc[0][2]); acc[0][3] = MFMA16(a0, b3, acc[0][3]);
        acc[1][0] = MFMA16(a1, b0, acc[1][0]); acc[1][1] = MFMA16(a1, b1, acc[1][1]);
        acc[1][2] = MFMA16(a1, b2, acc[1][2]); acc[1][3] = MFMA16(a1, b3, acc[1][3]);
    }
#pragma unroll
    for (int nt = 0; nt < 4; ++nt) {
        const int n = n0 + nt * 16 + lrow;           // C col = lane&15
        const float bz = bias[n];
        const int h = n >> 6, d = n & 63;
#pragma unroll
        for (int mt = 0; mt < 2; ++mt) {
            const int mb = m0 + mt * 16 + row4;      // C row = (lane>>4)*4 + j
            if (vmode == 0) {
#pragma unroll
                for (int j = 0; j < 4; ++j) {
                    const int m = mb + j;
                    const int b = m >> 10, l = m & 1023;
                    out[(((size_t)(b * 16 + h) << 10) + l) * 64 + d] = f2b(acc[mt][nt][j] + bz);
                }
            } else {
                const int b = mb >> 10, r = mb & 1023;
                short4v pk;
#pragma unroll
                for (int j = 0; j < 4; ++j) pk[j] = (short)f2b(acc[mt][nt][j] + bz);
                *(short4v*)&out[((((size_t)(b * 16 + h)) << 6) + d) * 1024 + r] = pk;
            }
        }
    }
}

// ---------------------------------------------------------------------------
// P3: headproj: x2[l][bh][e] = sum_d x[bh][l][d] * Wsx[d][e]   (bf16 out)
//               xbv[l][bh]   = sum_d x[bh][l][d] * bsx[d]
// grid 1024 (one l per block), 256 thr: (bh = t>>2, e0 = (t&3)*16)
// ---------------------------------------------------------------------------
__global__ __launch_bounds__(256) void headproj(
    const unsigned short* __restrict__ xh,  // [64][1024][64] bf16
    const float* __restrict__ Wsx,          // [64][64] f32
    const float* __restrict__ bsx,          // [64]
    unsigned short* __restrict__ x2b,       // [1024][64][64] bf16
    float* __restrict__ xbv) {              // [1024][64]
    __shared__ __align__(16) float Ws[64 * 64];
    __shared__ float bs[64];
    __shared__ __align__(16) unsigned short Xl[64 * 64];
    const int tid = threadIdx.x;
    const int l = blockIdx.x;
#pragma unroll
    for (int i = 0; i < 4; ++i)
        *(float4v*)&Ws[tid * 4 + i * 1024] = *(const float4v*)&Wsx[tid * 4 + i * 1024];
    if (tid < 64) bs[tid] = bsx[tid];
    {
        const int bhh = tid >> 2, dq = (tid & 3) * 16;
        const unsigned short* src = &xh[((size_t)bhh * 1024 + l) * 64 + dq];
        *(short8v*)&Xl[bhh * 64 + dq] = *(const short8v*)src;
        *(short8v*)&Xl[bhh * 64 + dq + 8] = *(const short8v*)(src + 8);
    }
    __syncthreads();
    const int bh = tid >> 2, e0 = (tid & 3) * 16;
    float acc[16] = {};
    float bacc = 0.f;
    for (int d = 0; d < 64; ++d) {
        const float xd = b2f(Xl[bh * 64 + d]);
        bacc += xd * bs[d];
        const float* wr = &Ws[d * 64 + e0];
#pragma unroll
        for (int e = 0; e < 16; e += 4) {
            float4v w = *(const float4v*)&wr[e];
            acc[e] += xd * w[0]; acc[e + 1] += xd * w[1];
            acc[e + 2] += xd * w[2]; acc[e + 3] += xd * w[3];
        }
    }
    short8v p0, p1;
#pragma unroll
    for (int e = 0; e < 8; ++e) { p0[e] = (short)f2b(acc[e]); p1[e] = (short)f2b(acc[e + 8]); }
    unsigned short* dst = &x2b[((size_t)l * 64 + bh) * 64 + e0];
    *(short8v*)dst = p0; *(short8v*)(dst + 8) = p1;
    if ((tid & 3) == 0) xbv[l * 64 + bh] = bacc;
}

// ---------------------------------------------------------------------------
// P4: T2: sb[l][bh][r] = sum_d S[l][r][d]*q2[l][bh][d] + qb[l][bh]   (write)
// grid (16, 64): x = r-tile(64), y = l-chunk(16). wave covers 16 r.
// ---------------------------------------------------------------------------
__global__ __launch_bounds__(256) void struct_t2(
    const float* __restrict__ S,              // [1024][1024][64]
    const unsigned short* __restrict__ q2b,   // [1024][64][64] bf16
    const float* __restrict__ qbv,            // [1024][64]
    unsigned short* __restrict__ sb) {        // [1024][64][1024] bf16
    const int wave = threadIdx.x >> 6, lane = threadIdx.x & 63;
    const int r0 = blockIdx.x * 64 + wave * 16;
    const int l0 = blockIdx.y * 16;
    const int lrow = lane & 15, g8 = (lane >> 4) << 3, row4 = (lane >> 4) << 2;
    for (int li = 0; li < 16; ++li) {
        const int l = l0 + li;
        const float* Sp = S + ((size_t)l * 1024 + (r0 + lrow)) * 64 + g8;
        short8v a0 = pack8(*(const float4v*)Sp, *(const float4v*)(Sp + 4));
        short8v a1 = pack8(*(const float4v*)(Sp + 32), *(const float4v*)(Sp + 36));
        const unsigned short* Bp = q2b + ((size_t)l * 64 + lrow) * 64 + g8;
        float4v acc[4] = {};
#pragma unroll
        for (int nt = 0; nt < 4; ++nt) {
            short8v b0 = *(const short8v*)(Bp + nt * 1024);
            short8v b1 = *(const short8v*)(Bp + nt * 1024 + 32);
            acc[nt] = MFMA16(a0, b0, acc[nt]);
            acc[nt] = MFMA16(a1, b1, acc[nt]);
        }
#pragma unroll
        for (int nt = 0; nt < 4; ++nt) {
            const int bh = nt * 16 + lrow;
            const float qb = qbv[l * 64 + bh];
            short4v pk;
#pragma unroll
            for (int j = 0; j < 4; ++j) pk[j] = (short)f2b(acc[nt][j] + qb);
            *(short4v*)&sb[((size_t)l * 64 + bh) * 1024 + r0 + row4] = pk;
        }
    }
}

// ---------------------------------------------------------------------------
// P5: T3: sb[l][bh][r] += sum_d S[l][r][d]*k2[r][bh][d] + kb[r][bh]  (RMW)
// grid (16, 64): x = r-chunk(64), y = l-tile(16). wave handles 16 r serially.
// ---------------------------------------------------------------------------
__global__ __launch_bounds__(256) void struct_t3(
    const float* __restrict__ S,
    const unsigned short* __restrict__ k2b,   // [1024][64][64] bf16
    const float* __restrict__ kbv,            // [1024][64]
    unsigned short* __restrict__ sb) {
    const int wave = threadIdx.x >> 6, lane = threadIdx.x & 63;
    const int l0 = blockIdx.y * 16;
    const int rb = blockIdx.x * 64 + wave * 16;
    const int lrow = lane & 15, g8 = (lane >> 4) << 3, row4 = (lane >> 4) << 2;
    for (int ri = 0; ri < 16; ++ri) {
        const int r = rb + ri;
        const float* Sp = S + ((size_t)(l0 + lrow) * 1024 + r) * 64 + g8;
        short8v a0 = pack8(*(const float4v*)Sp, *(const float4v*)(Sp + 4));
        short8v a1 = pack8(*(const float4v*)(Sp + 32), *(const float4v*)(Sp + 36));
        const unsigned short* Bp = k2b + ((size_t)r * 64 + lrow) * 64 + g8;
        float4v acc[4] = {};
#pragma unroll
        for (int nt = 0; nt < 4; ++nt) {
            short8v b0 = *(const short8v*)(Bp + nt * 1024);
            short8v b1 = *(const short8v*)(Bp + nt * 1024 + 32);
            acc[nt] = MFMA16(a0, b0, acc[nt]);
            acc[nt] = MFMA16(a1, b1, acc[nt]);
        }
#pragma unroll
        for (int nt = 0; nt < 4; ++nt) {
            const int bh = nt * 16 + lrow;
            const float kb = kbv[r * 64 + bh];
#pragma unroll
            for (int j = 0; j < 4; ++j) {
                const size_t idx = ((size_t)(l0 + row4 + j) * 64 + bh) * 1024 + r;
                sb[idx] = f2b(b2f(sb[idx]) + acc[nt][j] + kb);
            }
        }
    }
}

// ---------------------------------------------------------------------------
// P6: flash: scores[bh][l][r] = (QK + sb)*0.125 + mask; online softmax; PV.
// grid 2048 (XCD-swizzled -> bh, l-tile of 32), 256 thr = 4 waves.
// ---------------------------------------------------------------------------
__global__ __launch_bounds__(256) void flash_kernel(
    const unsigned short* __restrict__ qh,  // [64][1024][64] bf16
    const unsigned short* __restrict__ kh,
    const unsigned short* __restrict__ vT,  // [64][64][1024] bf16
    const unsigned short* __restrict__ sb,  // [1024][64][1024] bf16
    const float* __restrict__ mask,         // [4][1024]
    float* __restrict__ scores,             // [64][1024][1024]
    float* __restrict__ ctx) {              // [4][1024][1024]
    __shared__ __align__(16) float scL[32 * 64];
    __shared__ __align__(16) unsigned short pL[32 * 64];
    __shared__ float mL[32], sL[32], fL[32];
    const int bid = blockIdx.x;
    const int virt = (bid & 7) * 256 + (bid >> 3);
    const int bh = virt >> 5, lt = virt & 31;
    const int b = bh >> 4, h = bh & 15, l0 = lt * 32;
    const int tid = threadIdx.x, wave = tid >> 6, lane = tid & 63;
    const int lrow = lane & 15, g8 = (lane >> 4) << 3, row4 = (lane >> 4) << 2;
    // Q fragments (stay in registers)
    short8v qf[2][2];
#pragma unroll
    for (int mt = 0; mt < 2; ++mt)
#pragma unroll
        for (int ks = 0; ks < 2; ++ks)
            qf[mt][ks] = *(const short8v*)&qh[((size_t)bh * 1024 + l0 + mt * 16 + lrow) * 64 + ks * 32 + g8];
    float4v opv[2] = {};
    if (tid < 32) { mL[tid] = -3e38f; sL[tid] = 0.f; }
    __syncthreads();
    const int tl = tid >> 3, tr8 = tid & 7;
    const int keyS = ((tl >> 2) & 3) << 4;       // scL col swizzle key (f32 idx)
    const int keyP = (tl & 7) << 3;              // pL col swizzle key (u16 idx)
    for (int rt = 0; rt < 16; ++rt) {
        const int r0 = rt * 64;
        // --- QK^T (wave owns r-subtile = wave*16) ---
        float4v sacc[2] = {};
#pragma unroll
        for (int ks = 0; ks < 2; ++ks) {
            short8v kf = *(const short8v*)&kh[((size_t)bh * 1024 + r0 + wave * 16 + lrow) * 64 + ks * 32 + g8];
            sacc[0] = MFMA16(qf[0][ks], kf, sacc[0]);
            sacc[1] = MFMA16(qf[1][ks], kf, sacc[1]);
        }
#pragma unroll
        for (int mt = 0; mt < 2; ++mt)
#pragma unroll
            for (int j = 0; j < 4; ++j) {
                const int ll = mt * 16 + row4 + j;
                const int cc = wave * 16 + lrow;
                scL[ll * 64 + (cc ^ (((ll >> 2) & 3) << 4))] = sacc[mt][j];
            }
        __syncthreads();
        // --- score assembly + online softmax (thread = (tl, 8 r's)) ---
        float4v x0 = *(const float4v*)&scL[tl * 64 + ((tr8 * 8) ^ keyS)];
        float4v x1 = *(const float4v*)&scL[tl * 64 + ((tr8 * 8 + 4) ^ keyS)];
        short8v sbv = *(const short8v*)&sb[((size_t)(l0 + tl) * 64 + bh) * 1024 + r0 + tr8 * 8];
        float4v mk0 = *(const float4v*)&mask[(size_t)b * 1024 + r0 + tr8 * 8];
        float4v mk1 = *(const float4v*)&mask[(size_t)b * 1024 + r0 + tr8 * 8 + 4];
        float s8[8];
#pragma unroll
        for (int i = 0; i < 4; ++i) {
            s8[i]     = (x0[i] + b2f((unsigned short)sbv[i])) * 0.125f + mk0[i];
            s8[i + 4] = (x1[i] + b2f((unsigned short)sbv[i + 4])) * 0.125f + mk1[i];
        }
        {
            float4v o0, o1;
#pragma unroll
            for (int i = 0; i < 4; ++i) { o0[i] = s8[i]; o1[i] = s8[i + 4]; }
            float* sgp = &scores[((size_t)bh * 1024 + l0 + tl) * 1024 + r0 + tr8 * 8];
            *(float4v*)sgp = o0; *(float4v*)(sgp + 4) = o1;
        }
        float tm = s8[0];
#pragma unroll
        for (int i = 1; i < 8; ++i) tm = fmaxf(tm, s8[i]);
        tm = fmaxf(tm, __shfl_xor(tm, 1));
        tm = fmaxf(tm, __shfl_xor(tm, 2));
        tm = fmaxf(tm, __shfl_xor(tm, 4));
        const float mold = mL[tl];
        const float mnew = fmaxf(mold, tm);
        const float f = __expf(mold - mnew);
        float psum = 0.f;
        float p8[8];
#pragma unroll
        for (int i = 0; i < 8; ++i) { p8[i] = __expf(s8[i] - mnew); psum += p8[i]; }
        psum += __shfl_xor(psum, 1);
        psum += __shfl_xor(psum, 2);
        psum += __shfl_xor(psum, 4);
        if (tr8 == 0) { sL[tl] = sL[tl] * f + psum; mL[tl] = mnew; fL[tl] = f; }
        short8v pk;
#pragma unroll
        for (int i = 0; i < 8; ++i) pk[i] = (short)f2b(p8[i]);
        *(short8v*)&pL[tl * 64 + ((tr8 * 8) ^ keyP)] = pk;
        __syncthreads();
        // --- PV (wave owns d-subtile = wave*16) ---
#pragma unroll
        for (int mt = 0; mt < 2; ++mt)
#pragma unroll
            for (int j = 0; j < 4; ++j) opv[mt][j] *= fL[mt * 16 + row4 + j];
#pragma unroll
        for (int ks = 0; ks < 2; ++ks) {
            short8v pf0 = *(const short8v*)&pL[(lrow) * 64 + ((ks * 32 + g8) ^ ((lrow & 7) << 3))];
            short8v pf1 = *(const short8v*)&pL[(16 + lrow) * 64 + ((ks * 32 + g8) ^ ((lrow & 7) << 3))];
            short8v vf = *(const short8v*)&vT[((size_t)bh * 64 + wave * 16 + lrow) * 1024 + r0 + ks * 32 + g8];
            opv[0] = MFMA16(pf0, vf, opv[0]);
            opv[1] = MFMA16(pf1, vf, opv[1]);
        }
    }
    // epilogue: ctx[b][l][h*64+d] = O / s
#pragma unroll
    for (int mt = 0; mt < 2; ++mt)
#pragma unroll
        for (int j = 0; j < 4; ++j) {
            const int l = mt * 16 + row4 + j;
            const float inv = 1.f / sL[l];
            const int d = wave * 16 + lrow;
            ctx[((size_t)b * 1024 + l0 + l) * 1024 + h * 64 + d] = opv[mt][j] * inv;
        }
}

// ---------------------------------------------------------------------------
extern "C" void kernel_launch(void* const* d_in, const int* in_sizes, int n_in,
                              void* d_out, int out_size, void* d_ws, size_t ws_size,
                              hipStream_t stream) {
    (void)in_sizes; (void)n_in; (void)out_size; (void)ws_size;
    const float* hidden = (const float*)d_in[0];
    const float* mask   = (const float*)d_in[1];
    const float* S      = (const float*)d_in[2];
    const float* Wq  = (const float*)d_in[3];  const float* bq  = (const float*)d_in[4];
    const float* Wk  = (const float*)d_in[5];  const float* bk  = (const float*)d_in[6];
    const float* Wv  = (const float*)d_in[7];  const float* bv  = (const float*)d_in[8];
    const float* Wsq = (const float*)d_in[9];  const float* bsq = (const float*)d_in[10];
    const float* Wsk = (const float*)d_in[11]; const float* bsk = (const float*)d_in[12];

    float* ctx    = (float*)d_out;
    float* scores = ctx + (size_t)4 * 1024 * 1024 * 1024 / 1024;  // 4*1024*1024 floats
    // (= ctx + 4194304)

    char* ws = (char*)d_ws;
    unsigned short* sbuf = (unsigned short*)ws;                 // [1024][64][1024] bf16, 128 MB
    // stage-1 temporaries alias the (not-yet-live) sbuf region:
    unsigned short* hb  = (unsigned short*)ws;                  // 8 MB
    unsigned short* Wqb = (unsigned short*)(ws + (8u << 20));   // 2 MB
    unsigned short* Wkb = (unsigned short*)(ws + (10u << 20));
    unsigned short* Wvb = (unsigned short*)(ws + (12u << 20));
    unsigned short* qh  = (unsigned short*)(ws + (size_t)(128u) * 1024 * 1024);
    unsigned short* kh  = qh  + (size_t)4 * 1024 * 1024;
    unsigned short* vT  = kh  + (size_t)4 * 1024 * 1024;
    unsigned short* q2b = vT  + (size_t)4 * 1024 * 1024;
    unsigned short* k2b = q2b + (size_t)4 * 1024 * 1024;
    float* qbv = (float*)(k2b + (size_t)4 * 1024 * 1024);
    float* kbv = qbv + 65536;

    pack_bf16<<<2048, 256, 0, stream>>>(hidden, hb, 524288);
    pack_bf16<<<512, 256, 0, stream>>>(Wq, Wqb, 131072);
    pack_bf16<<<512, 256, 0, stream>>>(Wk, Wkb, 131072);
    pack_bf16<<<512, 256, 0, stream>>>(Wv, Wvb, 131072);
    qkv_gemm<<<dim3(16, 32), 256, 0, stream>>>(hb, Wqb, bq, qh, 0);
    qkv_gemm<<<dim3(16, 32), 256, 0, stream>>>(hb, Wkb, bk, kh, 0);
    qkv_gemm<<<dim3(16, 32), 256, 0, stream>>>(hb, Wvb, bv, vT, 1);
    headproj<<<1024, 256, 0, stream>>>(qh, Wsq, bsq, q2b, qbv);
    headproj<<<1024, 256, 0, stream>>>(kh, Wsk, bsk, k2b, kbv);
    struct_t2<<<dim3(16, 64), 256, 0, stream>>>(S, q2b, qbv, sbuf);
    struct_t3<<<dim3(16, 64), 256, 0, stream>>>(S, k2b, kbv, sbuf);
    flash_kernel<<<2048, 256, 0, stream>>>(qh, kh, vT, sbuf, mask, scores, ctx);
}

// Round 3
// 567.350 us; speedup vs baseline: 4.4097x; 3.0299x over previous
//
#include <hip/hip_runtime.h>

typedef __attribute__((ext_vector_type(8))) short short8v;
typedef __attribute__((ext_vector_type(4))) short short4v;
typedef __attribute__((ext_vector_type(4))) float float4v;

#define MFMA16(a,b,c) __builtin_amdgcn_mfma_f32_16x16x32_bf16(a,b,c,0,0,0)

__device__ __forceinline__ unsigned short f2b(float f) {
    union { float f; unsigned u; } v; v.f = f;
    unsigned r = v.u + 0x7FFFu + ((v.u >> 16) & 1u);
    return (unsigned short)(r >> 16);
}
__device__ __forceinline__ float b2f(unsigned short s) {
    union { unsigned u; float f; } v; v.u = ((unsigned)s) << 16;
    return v.f;
}
__device__ __forceinline__ short8v pack8(float4v a, float4v b) {
    short8v o;
    o[0]=(short)f2b(a[0]); o[1]=(short)f2b(a[1]); o[2]=(short)f2b(a[2]); o[3]=(short)f2b(a[3]);
    o[4]=(short)f2b(b[0]); o[5]=(short)f2b(b[1]); o[6]=(short)f2b(b[2]); o[7]=(short)f2b(b[3]);
    return o;
}

// ---------------------------------------------------------------------------
// P1: f32 -> bf16 pack (8 elems/thread)
// ---------------------------------------------------------------------------
__global__ __launch_bounds__(256) void pack_bf16(
    const float* __restrict__ in, unsigned short* __restrict__ out, int n8) {
    int i = blockIdx.x * 256 + threadIdx.x;
    if (i < n8) {
        float4v a = *(const float4v*)&in[(size_t)i * 8];
        float4v b = *(const float4v*)&in[(size_t)i * 8 + 4];
        *(short8v*)&out[(size_t)i * 8] = pack8(a, b);
    }
}

// ---------------------------------------------------------------------------
// P2: C = hb @ W^T + bias  (MFMA bf16, operands direct from global)
//     vmode 0: out[bh][l][d] bf16      (qh / kh)
//     vmode 1: out[bh][d][r] bf16      (vT)
// ---------------------------------------------------------------------------
__global__ __launch_bounds__(256) void qkv_gemm(
    const unsigned short* __restrict__ A,   // [4096][1024] bf16
    const unsigned short* __restrict__ W,   // [1024][1024] bf16 [n][k]
    const float* __restrict__ bias,         // [1024]
    unsigned short* __restrict__ out, int vmode) {
    const int wave = threadIdx.x >> 6, lane = threadIdx.x & 63;
    const int m0 = blockIdx.y * 128 + wave * 32;
    const int n0 = blockIdx.x * 64;
    const int lrow = lane & 15, g8 = (lane >> 4) << 3, row4 = (lane >> 4) << 2;
    float4v acc[2][4] = {};
    const unsigned short* Ap = A + (size_t)(m0 + lrow) * 1024 + g8;
    const unsigned short* Wp = W + (size_t)(n0 + lrow) * 1024 + g8;
#pragma unroll 2
    for (int k0 = 0; k0 < 1024; k0 += 32) {
        short8v a0 = *(const short8v*)(Ap + k0);
        short8v a1 = *(const short8v*)(Ap + 16 * 1024 + k0);
        short8v b0 = *(const short8v*)(Wp + k0);
        short8v b1 = *(const short8v*)(Wp + 16 * 1024 + k0);
        short8v b2 = *(const short8v*)(Wp + 32 * 1024 + k0);
        short8v b3 = *(const short8v*)(Wp + 48 * 1024 + k0);
        acc[0][0] = MFMA16(a0, b0, acc[0][0]); acc[0][1] = MFMA16(a0, b1, acc[0][1]);
        acc[0][2] = MFMA16(a0, b2, acc[0][2]); acc[0][3] = MFMA16(a0, b3, acc[0][3]);
        acc[1][0] = MFMA16(a1, b0, acc[1][0]); acc[1][1] = MFMA16(a1, b1, acc[1][1]);
        acc[1][2] = MFMA16(a1, b2, acc[1][2]); acc[1][3] = MFMA16(a1, b3, acc[1][3]);
    }
#pragma unroll
    for (int nt = 0; nt < 4; ++nt) {
        const int n = n0 + nt * 16 + lrow;           // C col = lane&15
        const float bz = bias[n];
        const int h = n >> 6, d = n & 63;
#pragma unroll
        for (int mt = 0; mt < 2; ++mt) {
            const int mb = m0 + mt * 16 + row4;      // C row = (lane>>4)*4 + j
            if (vmode == 0) {
#pragma unroll
                for (int j = 0; j < 4; ++j) {
                    const int m = mb + j;
                    const int b = m >> 10, l = m & 1023;
                    out[(((size_t)(b * 16 + h) << 10) + l) * 64 + d] = f2b(acc[mt][nt][j] + bz);
                }
            } else {
                const int b = mb >> 10, r = mb & 1023;
                short4v pk;
#pragma unroll
                for (int j = 0; j < 4; ++j) pk[j] = (short)f2b(acc[mt][nt][j] + bz);
                *(short4v*)&out[((((size_t)(b * 16 + h)) << 6) + d) * 1024 + r] = pk;
            }
        }
    }
}

// ---------------------------------------------------------------------------
// P3: headproj: x2[l][bh][e] = sum_d x[bh][l][d] * Wsx[d][e]   (bf16 out)
//               xbv[l][bh]   = sum_d x[bh][l][d] * bsx[d]
// ---------------------------------------------------------------------------
__global__ __launch_bounds__(256) void headproj(
    const unsigned short* __restrict__ xh,  // [64][1024][64] bf16
    const float* __restrict__ Wsx,          // [64][64] f32
    const float* __restrict__ bsx,          // [64]
    unsigned short* __restrict__ x2b,       // [1024][64][64] bf16
    float* __restrict__ xbv) {              // [1024][64]
    __shared__ __align__(16) float Ws[64 * 64];
    __shared__ float bs[64];
    __shared__ __align__(16) unsigned short Xl[64 * 64];
    const int tid = threadIdx.x;
    const int l = blockIdx.x;
#pragma unroll
    for (int i = 0; i < 4; ++i)
        *(float4v*)&Ws[tid * 4 + i * 1024] = *(const float4v*)&Wsx[tid * 4 + i * 1024];
    if (tid < 64) bs[tid] = bsx[tid];
    {
        const int bhh = tid >> 2, dq = (tid & 3) * 16;
        const unsigned short* src = &xh[((size_t)bhh * 1024 + l) * 64 + dq];
        *(short8v*)&Xl[bhh * 64 + dq] = *(const short8v*)src;
        *(short8v*)&Xl[bhh * 64 + dq + 8] = *(const short8v*)(src + 8);
    }
    __syncthreads();
    const int bh = tid >> 2, e0 = (tid & 3) * 16;
    float acc[16] = {};
    float bacc = 0.f;
    for (int d = 0; d < 64; ++d) {
        const float xd = b2f(Xl[bh * 64 + d]);
        bacc += xd * bs[d];
        const float* wr = &Ws[d * 64 + e0];
#pragma unroll
        for (int e = 0; e < 16; e += 4) {
            float4v w = *(const float4v*)&wr[e];
            acc[e] += xd * w[0]; acc[e + 1] += xd * w[1];
            acc[e + 2] += xd * w[2]; acc[e + 3] += xd * w[3];
        }
    }
    short8v p0, p1;
#pragma unroll
    for (int e = 0; e < 8; ++e) { p0[e] = (short)f2b(acc[e]); p1[e] = (short)f2b(acc[e + 8]); }
    unsigned short* dst = &x2b[((size_t)l * 64 + bh) * 64 + e0];
    *(short8v*)dst = p0; *(short8v*)(dst + 8) = p1;
    if ((tid & 3) == 0) xbv[l * 64 + bh] = bacc;
}

// ---------------------------------------------------------------------------
// P4 (NEW): fused structure-bias kernel, no RMW.
//   sb[l][bh][r] = sum_d S[l][r][d]*(q2[l][bh][d] + k2[r][bh][d]) + qb + kb
// Block = 16l x 16r tile, 4 waves; wave w owns bh in [16w,16w+16).
//   phase1: S tile -> LDS bf16 (XOR-swizzled, serves both row-groupings)
//   phase2: T3 (A rows = l, per ri) -> regs -> per-wave LDS t3[l][bh][ri]
//   phase3: T2 per li (A rows = r) + t3 + qb + kb -> per-wave LDS transpose
//           -> 32B r-contiguous global writes
// ---------------------------------------------------------------------------
__global__ __launch_bounds__(256) void struct_fused(
    const float* __restrict__ S,              // [1024][1024][64]
    const unsigned short* __restrict__ q2b,   // [1024][64][64] bf16
    const unsigned short* __restrict__ k2b,   // [1024][64][64] bf16
    const float* __restrict__ qbv,            // [1024][64]
    const float* __restrict__ kbv,            // [1024][64]
    unsigned short* __restrict__ sb) {        // [1024][64][1024] bf16
    __shared__ __align__(16) unsigned short Ssh[256 * 64];     // 32 KB
    __shared__ __align__(16) unsigned short t3sh[4 * 4096];    // 32 KB
    __shared__ __align__(16) unsigned short outsh[4][2][256];  // 4 KB
    const int tid = threadIdx.x;
    const int w = tid >> 6, lane = tid & 63;
    const int lrow = lane & 15, g = lane >> 4;
    const int g8 = g << 3, row4 = g << 2;
    const int w16 = w << 4;
    const int r0 = blockIdx.x << 4, l0 = blockIdx.y << 4;
    const int wbase = w << 12;

    // ---- phase 1: stage S tile (row = li*16+ri owns 64 f32 = 256 B) ----
    {
        const int row = tid;
        const int key = (row ^ (row >> 4)) & 7;
        const size_t gbase = ((size_t)(l0 + (row >> 4)) * 1024 + (r0 + (row & 15))) * 64;
#pragma unroll
        for (int c = 0; c < 8; ++c) {
            float4v x = *(const float4v*)&S[gbase + c * 8];
            float4v y = *(const float4v*)&S[gbase + c * 8 + 4];
            *(short8v*)&Ssh[row * 64 + ((c ^ key) << 3)] = pack8(x, y);
        }
    }
    // qb/kb into regs
    float kbreg[4], qbreg[16];
#pragma unroll
    for (int j = 0; j < 4; ++j)
        kbreg[j] = kbv[(size_t)(r0 + row4 + j) * 64 + w16 + lrow];
#pragma unroll
    for (int li = 0; li < 16; ++li)
        qbreg[li] = qbv[(size_t)(l0 + li) * 64 + w16 + lrow];
    __syncthreads();

    // ---- phase 2: T3.  A rows = l (lane&15), per ri; B = k2[r0+ri][bh] ----
    float4v c3[16];
#pragma unroll
    for (int ri = 0; ri < 16; ++ri) {
        const int rowA = lrow * 16 + ri;
        const int keyA = (ri ^ lrow) & 7;
        short8v a0 = *(const short8v*)&Ssh[rowA * 64 + ((g ^ keyA) << 3)];
        short8v a1 = *(const short8v*)&Ssh[rowA * 64 + (((4 + g) ^ keyA) << 3)];
        const unsigned short* Bp = k2b + ((size_t)(r0 + ri) * 64 + w16 + lrow) * 64 + g8;
        short8v b0 = *(const short8v*)Bp;
        short8v b1 = *(const short8v*)(Bp + 32);
        float4v acc = {};
        acc = MFMA16(a0, b0, acc);
        acc = MFMA16(a1, b1, acc);
        c3[ri] = acc;
    }
    // dump C3 -> t3sh[l][bh][ri] (per-wave region, chunk-swizzled)
#pragma unroll
    for (int j = 0; j < 4; ++j) {
        const int l = row4 + j;
#pragma unroll
        for (int rq = 0; rq < 2; ++rq) {
            short8v pk;
#pragma unroll
            for (int i = 0; i < 8; ++i) pk[i] = (short)f2b(c3[rq * 8 + i][j]);
            const int chunk = rq ^ ((lrow >> 2) & 1);
            *(short8v*)&t3sh[wbase + (l * 16 + lrow) * 16 + (chunk << 3)] = pk;
        }
    }
    asm volatile("s_waitcnt lgkmcnt(0)" ::: "memory");

    // ---- phase 3: T2 per li + combine + transposed write-out ----
#pragma unroll
    for (int li = 0; li < 16; ++li) {
        const int rowA = li * 16 + lrow;
        const int keyA = (li ^ lrow) & 7;
        short8v a0 = *(const short8v*)&Ssh[rowA * 64 + ((g ^ keyA) << 3)];
        short8v a1 = *(const short8v*)&Ssh[rowA * 64 + (((4 + g) ^ keyA) << 3)];
        const unsigned short* Bp = q2b + ((size_t)(l0 + li) * 64 + w16 + lrow) * 64 + g8;
        short8v b0 = *(const short8v*)Bp;
        short8v b1 = *(const short8v*)(Bp + 32);
        float4v c2 = {};
        c2 = MFMA16(a0, b0, c2);
        c2 = MFMA16(a1, b1, c2);
        // t3 read: (l=li, bh=lrow, ri=row4..row4+3)
        const int phys = (((row4 >> 3) ^ ((lrow >> 2) & 1)) << 3) | (row4 & 7);
        short4v t3v = *(const short4v*)&t3sh[wbase + (li * 16 + lrow) * 16 + phys];
        const float qb = qbreg[li];
        short4v outv;
#pragma unroll
        for (int j = 0; j < 4; ++j)
            outv[j] = (short)f2b(c2[j] + b2f((unsigned short)t3v[j]) + qb + kbreg[j]);
        // transpose bounce: write (bh=lrow, r=row4..+3), read (bh=lane>>2, rq=lane&3)
        *(short4v*)&outsh[w][li & 1][lrow * 16 + (row4 ^ (((lrow >> 2) & 3) << 2))] = outv;
        asm volatile("s_waitcnt lgkmcnt(0)" ::: "memory");
        const int obh = lane >> 2, orq = lane & 3;
        short4v ov = *(const short4v*)&outsh[w][li & 1][obh * 16 + ((orq << 2) ^ (((obh >> 2) & 3) << 2))];
        *(short4v*)&sb[((size_t)(l0 + li) * 64 + w16 + obh) * 1024 + r0 + (orq << 2)] = ov;
    }
}

// ---------------------------------------------------------------------------
// P6: flash: scores[bh][l][r] = (QK + sb)*0.125 + mask; online softmax; PV.
// ---------------------------------------------------------------------------
__global__ __launch_bounds__(256) void flash_kernel(
    const unsigned short* __restrict__ qh,  // [64][1024][64] bf16
    const unsigned short* __restrict__ kh,
    const unsigned short* __restrict__ vT,  // [64][64][1024] bf16
    const unsigned short* __restrict__ sb,  // [1024][64][1024] bf16
    const float* __restrict__ mask,         // [4][1024]
    float* __restrict__ scores,             // [64][1024][1024]
    float* __restrict__ ctx) {              // [4][1024][1024]
    __shared__ __align__(16) float scL[32 * 64];
    __shared__ __align__(16) unsigned short pL[32 * 64];
    __shared__ float mL[32], sL[32], fL[32];
    const int bid = blockIdx.x;
    const int virt = (bid & 7) * 256 + (bid >> 3);
    const int bh = virt >> 5, lt = virt & 31;
    const int b = bh >> 4, h = bh & 15, l0 = lt * 32;
    const int tid = threadIdx.x, wave = tid >> 6, lane = tid & 63;
    const int lrow = lane & 15, g8 = (lane >> 4) << 3, row4 = (lane >> 4) << 2;
    short8v qf[2][2];
#pragma unroll
    for (int mt = 0; mt < 2; ++mt)
#pragma unroll
        for (int ks = 0; ks < 2; ++ks)
            qf[mt][ks] = *(const short8v*)&qh[((size_t)bh * 1024 + l0 + mt * 16 + lrow) * 64 + ks * 32 + g8];
    float4v opv[2] = {};
    if (tid < 32) { mL[tid] = -3e38f; sL[tid] = 0.f; }
    __syncthreads();
    const int tl = tid >> 3, tr8 = tid & 7;
    const int keyS = ((tl >> 2) & 3) << 4;
    const int keyP = (tl & 7) << 3;
    for (int rt = 0; rt < 16; ++rt) {
        const int r0 = rt * 64;
        float4v sacc[2] = {};
#pragma unroll
        for (int ks = 0; ks < 2; ++ks) {
            short8v kf = *(const short8v*)&kh[((size_t)bh * 1024 + r0 + wave * 16 + lrow) * 64 + ks * 32 + g8];
            sacc[0] = MFMA16(qf[0][ks], kf, sacc[0]);
            sacc[1] = MFMA16(qf[1][ks], kf, sacc[1]);
        }
#pragma unroll
        for (int mt = 0; mt < 2; ++mt)
#pragma unroll
            for (int j = 0; j < 4; ++j) {
                const int ll = mt * 16 + row4 + j;
                const int cc = wave * 16 + lrow;
                scL[ll * 64 + (cc ^ (((ll >> 2) & 3) << 4))] = sacc[mt][j];
            }
        __syncthreads();
        float4v x0 = *(const float4v*)&scL[tl * 64 + ((tr8 * 8) ^ keyS)];
        float4v x1 = *(const float4v*)&scL[tl * 64 + ((tr8 * 8 + 4) ^ keyS)];
        short8v sbv = *(const short8v*)&sb[((size_t)(l0 + tl) * 64 + bh) * 1024 + r0 + tr8 * 8];
        float4v mk0 = *(const float4v*)&mask[(size_t)b * 1024 + r0 + tr8 * 8];
        float4v mk1 = *(const float4v*)&mask[(size_t)b * 1024 + r0 + tr8 * 8 + 4];
        float s8[8];
#pragma unroll
        for (int i = 0; i < 4; ++i) {
            s8[i]     = (x0[i] + b2f((unsigned short)sbv[i])) * 0.125f + mk0[i];
            s8[i + 4] = (x1[i] + b2f((unsigned short)sbv[i + 4])) * 0.125f + mk1[i];
        }
        {
            float4v o0, o1;
#pragma unroll
            for (int i = 0; i < 4; ++i) { o0[i] = s8[i]; o1[i] = s8[i + 4]; }
            float* sgp = &scores[((size_t)bh * 1024 + l0 + tl) * 1024 + r0 + tr8 * 8];
            *(float4v*)sgp = o0; *(float4v*)(sgp + 4) = o1;
        }
        float tm = s8[0];
#pragma unroll
        for (int i = 1; i < 8; ++i) tm = fmaxf(tm, s8[i]);
        tm = fmaxf(tm, __shfl_xor(tm, 1));
        tm = fmaxf(tm, __shfl_xor(tm, 2));
        tm = fmaxf(tm, __shfl_xor(tm, 4));
        const float mold = mL[tl];
        const float mnew = fmaxf(mold, tm);
        const float f = __expf(mold - mnew);
        float psum = 0.f;
        float p8[8];
#pragma unroll
        for (int i = 0; i < 8; ++i) { p8[i] = __expf(s8[i] - mnew); psum += p8[i]; }
        psum += __shfl_xor(psum, 1);
        psum += __shfl_xor(psum, 2);
        psum += __shfl_xor(psum, 4);
        if (tr8 == 0) { sL[tl] = sL[tl] * f + psum; mL[tl] = mnew; fL[tl] = f; }
        short8v pk;
#pragma unroll
        for (int i = 0; i < 8; ++i) pk[i] = (short)f2b(p8[i]);
        *(short8v*)&pL[tl * 64 + ((tr8 * 8) ^ keyP)] = pk;
        __syncthreads();
#pragma unroll
        for (int mt = 0; mt < 2; ++mt)
#pragma unroll
            for (int j = 0; j < 4; ++j) opv[mt][j] *= fL[mt * 16 + row4 + j];
#pragma unroll
        for (int ks = 0; ks < 2; ++ks) {
            short8v pf0 = *(const short8v*)&pL[(lrow) * 64 + ((ks * 32 + g8) ^ ((lrow & 7) << 3))];
            short8v pf1 = *(const short8v*)&pL[(16 + lrow) * 64 + ((ks * 32 + g8) ^ ((lrow & 7) << 3))];
            short8v vf = *(const short8v*)&vT[((size_t)bh * 64 + wave * 16 + lrow) * 1024 + r0 + ks * 32 + g8];
            opv[0] = MFMA16(pf0, vf, opv[0]);
            opv[1] = MFMA16(pf1, vf, opv[1]);
        }
    }
#pragma unroll
    for (int mt = 0; mt < 2; ++mt)
#pragma unroll
        for (int j = 0; j < 4; ++j) {
            const int l = mt * 16 + row4 + j;
            const float inv = 1.f / sL[l];
            const int d = wave * 16 + lrow;
            ctx[((size_t)b * 1024 + l0 + l) * 1024 + h * 64 + d] = opv[mt][j] * inv;
        }
}

// ---------------------------------------------------------------------------
extern "C" void kernel_launch(void* const* d_in, const int* in_sizes, int n_in,
                              void* d_out, int out_size, void* d_ws, size_t ws_size,
                              hipStream_t stream) {
    (void)in_sizes; (void)n_in; (void)out_size; (void)ws_size;
    const float* hidden = (const float*)d_in[0];
    const float* mask   = (const float*)d_in[1];
    const float* S      = (const float*)d_in[2];
    const float* Wq  = (const float*)d_in[3];  const float* bq  = (const float*)d_in[4];
    const float* Wk  = (const float*)d_in[5];  const float* bk  = (const float*)d_in[6];
    const float* Wv  = (const float*)d_in[7];  const float* bv  = (const float*)d_in[8];
    const float* Wsq = (const float*)d_in[9];  const float* bsq = (const float*)d_in[10];
    const float* Wsk = (const float*)d_in[11]; const float* bsk = (const float*)d_in[12];

    float* ctx    = (float*)d_out;
    float* scores = ctx + (size_t)4 * 1024 * 1024;

    char* ws = (char*)d_ws;
    unsigned short* sbuf = (unsigned short*)ws;                 // [1024][64][1024] bf16, 128 MB
    unsigned short* hb  = (unsigned short*)ws;                  // stage-1 temps alias sbuf
    unsigned short* Wqb = (unsigned short*)(ws + (8u << 20));
    unsigned short* Wkb = (unsigned short*)(ws + (10u << 20));
    unsigned short* Wvb = (unsigned short*)(ws + (12u << 20));
    unsigned short* qh  = (unsigned short*)(ws + (size_t)(128u) * 1024 * 1024);
    unsigned short* kh  = qh  + (size_t)4 * 1024 * 1024;
    unsigned short* vT  = kh  + (size_t)4 * 1024 * 1024;
    unsigned short* q2b = vT  + (size_t)4 * 1024 * 1024;
    unsigned short* k2b = q2b + (size_t)4 * 1024 * 1024;
    float* qbv = (float*)(k2b + (size_t)4 * 1024 * 1024);
    float* kbv = qbv + 65536;

    pack_bf16<<<2048, 256, 0, stream>>>(hidden, hb, 524288);
    pack_bf16<<<512, 256, 0, stream>>>(Wq, Wqb, 131072);
    pack_bf16<<<512, 256, 0, stream>>>(Wk, Wkb, 131072);
    pack_bf16<<<512, 256, 0, stream>>>(Wv, Wvb, 131072);
    qkv_gemm<<<dim3(16, 32), 256, 0, stream>>>(hb, Wqb, bq, qh, 0);
    qkv_gemm<<<dim3(16, 32), 256, 0, stream>>>(hb, Wkb, bk, kh, 0);
    qkv_gemm<<<dim3(16, 32), 256, 0, stream>>>(hb, Wvb, bv, vT, 1);
    headproj<<<1024, 256, 0, stream>>>(qh, Wsq, bsq, q2b, qbv);
    headproj<<<1024, 256, 0, stream>>>(kh, Wsk, bsk, k2b, kbv);
    struct_fused<<<dim3(64, 64), 256, 0, stream>>>(S, q2b, k2b, qbv, kbv, sbuf);
    flash_kernel<<<2048, 256, 0, stream>>>(qh, kh, vT, sbuf, mask, scores, ctx);
}